// Round 7
// baseline (587.871 us; speedup 1.0000x reference)
//
#include <hip/hip_runtime.h>
#include <math.h>

#define D_MODEL 512
#define N_HEADS 8
#define D_K     64
#define D_EDGE  16
#define D_FF    2048
#define B_SZ    4
#define N_SEQ   1024
#define M_ROWS  (B_SZ * N_SEQ)
#define LN_EPS  1e-5f
#define JSPLIT  4
#define ROWS_T  (B_SZ * N_HEADS * N_SEQ)   // 32768

typedef __attribute__((ext_vector_type(4))) float f32x4;
typedef __attribute__((ext_vector_type(8))) short s16x8;
typedef __attribute__((ext_vector_type(8))) unsigned short u16x8;
typedef __attribute__((ext_vector_type(4))) unsigned short u16x4;

__device__ __forceinline__ unsigned short f2bf(float f) {
  union { float f; unsigned u; } x; x.f = f;
  unsigned r = x.u + 0x7fffu + ((x.u >> 16) & 1u);   // RNE
  return (unsigned short)(r >> 16);
}
__device__ __forceinline__ float bf2f(unsigned short u) {
  union { unsigned u; float f; } x; x.u = ((unsigned)u) << 16;
  return x.f;
}
__device__ __forceinline__ float gelu_exact(float v) {
  return 0.5f * v * (1.0f + erff(v * 0.70710678118654752440f));
}

// ---------------- fused weight cast fp32 -> bf16 (wq|wk|wv | wo | w1 | w2) ----------------
__global__ __launch_bounds__(256) void cast_weights(
    const float* __restrict__ wq, const float* __restrict__ wk, const float* __restrict__ wv,
    const float* __restrict__ wo, const float* __restrict__ w1, const float* __restrict__ w2,
    unsigned short* __restrict__ wbf)
{
  const int i4 = blockIdx.x * 256 + threadIdx.x;   // float4 index, 786432 total
  const float* src; int off4;
  if (i4 < 196608) {
    const int sub = i4 >> 16;                       // 0..2
    src = (sub == 0) ? wq : ((sub == 1) ? wk : wv);
    off4 = i4 & 65535;
  } else if (i4 < 262144) { src = wo; off4 = i4 - 196608; }
  else if (i4 < 524288)   { src = w1; off4 = i4 - 262144; }
  else                    { src = w2; off4 = i4 - 524288; }
  const float4 v = ((const float4*)src)[off4];
  u16x4 p = { f2bf(v.x), f2bf(v.y), f2bf(v.z), f2bf(v.w) };
  *(u16x4*)(wbf + (size_t)i4 * 4) = p;
}

// ---------------- LayerNorm: one wave per row, bf16 out ----------------
__global__ __launch_bounds__(256) void ln_kernel(
    const float* __restrict__ x, const float* __restrict__ g,
    const float* __restrict__ bb, unsigned short* __restrict__ out)
{
  const int row  = blockIdx.x * 4 + (threadIdx.x >> 6);
  const int lane = threadIdx.x & 63;
  const float4* xr = (const float4*)(x + (size_t)row * D_MODEL);
  float4 v0 = xr[lane * 2 + 0];
  float4 v1 = xr[lane * 2 + 1];
  float s  = v0.x + v0.y + v0.z + v0.w + v1.x + v1.y + v1.z + v1.w;
  float ss = v0.x*v0.x + v0.y*v0.y + v0.z*v0.z + v0.w*v0.w
           + v1.x*v1.x + v1.y*v1.y + v1.z*v1.z + v1.w*v1.w;
  #pragma unroll
  for (int off = 32; off >= 1; off >>= 1) {
    s  += __shfl_xor(s, off);
    ss += __shfl_xor(ss, off);
  }
  const float mu  = s * (1.0f / D_MODEL);
  const float var = ss * (1.0f / D_MODEL) - mu * mu;
  const float r   = rsqrtf(var + LN_EPS);
  const float4* gp = (const float4*)g;
  const float4* bp = (const float4*)bb;
  float4 g0 = gp[lane*2+0], g1v = gp[lane*2+1];
  float4 b0 = bp[lane*2+0], b1v = bp[lane*2+1];
  u16x4 oa = { f2bf((v0.x - mu) * r * g0.x + b0.x),
               f2bf((v0.y - mu) * r * g0.y + b0.y),
               f2bf((v0.z - mu) * r * g0.z + b0.z),
               f2bf((v0.w - mu) * r * g0.w + b0.w) };
  u16x4 ob = { f2bf((v1.x - mu) * r * g1v.x + b1v.x),
               f2bf((v1.y - mu) * r * g1v.y + b1v.y),
               f2bf((v1.z - mu) * r * g1v.z + b1v.z),
               f2bf((v1.w - mu) * r * g1v.w + b1v.w) };
  unsigned short* orow = out + (size_t)row * D_MODEL + lane * 8;
  *(u16x4*)(orow)     = oa;
  *(u16x4*)(orow + 4) = ob;
}

// ---------------- bf16 MFMA GEMM (BM=128,BN=64,BK=64): C = A @ W^T ----------------
template<int ACT, int RES, int OBF, int HB>
__global__ __launch_bounds__(256, 4) void gemm_bf16(
    const unsigned short* __restrict__ A, const unsigned short* __restrict__ W,
    const float* __restrict__ bias, const float* __restrict__ res,
    void* __restrict__ Cv, int Nout, int K)
{
  __shared__ unsigned short As[128 * 64];
  __shared__ unsigned short Ws[64 * 64];
  const int tid  = threadIdx.x;
  const int w    = tid >> 6;
  const int lane = tid & 63;
  const int g    = lane >> 4;
  const int c    = lane & 15;
  const int row0 = blockIdx.x * 128;
  const int col0 = blockIdx.y * 64;
  const f32x4 z = { 0.f, 0.f, 0.f, 0.f };
  f32x4 acc[2][4];
  #pragma unroll
  for (int fm = 0; fm < 2; ++fm)
    #pragma unroll
    for (int fn = 0; fn < 4; ++fn) acc[fm][fn] = z;

  for (int k0 = 0; k0 < K; k0 += 64) {
    #pragma unroll
    for (int i = 0; i < 4; ++i) {
      const int flat = i * 256 + tid;
      __builtin_amdgcn_global_load_lds(
          (const __attribute__((address_space(1))) void*)(A + (size_t)(row0 + (flat >> 3)) * K + k0 + (flat & 7) * 8),
          (__attribute__((address_space(3))) void*)(&As[flat * 8]), 16, 0, 0);
    }
    #pragma unroll
    for (int i = 0; i < 2; ++i) {
      const int flat = i * 256 + tid;
      __builtin_amdgcn_global_load_lds(
          (const __attribute__((address_space(1))) void*)(W + (size_t)(col0 + (flat >> 3)) * K + k0 + (flat & 7) * 8),
          (__attribute__((address_space(3))) void*)(&Ws[flat * 8]), 16, 0, 0);
    }
    __syncthreads();
    #pragma unroll
    for (int kk = 0; kk < 2; ++kk) {
      const s16x8 a0 = *(const s16x8*)&As[(w * 32 + c) * 64 + kk * 32 + 8 * g];
      const s16x8 a1 = *(const s16x8*)&As[(w * 32 + 16 + c) * 64 + kk * 32 + 8 * g];
      #pragma unroll
      for (int fn = 0; fn < 4; ++fn) {
        const s16x8 bfr = *(const s16x8*)&Ws[(fn * 16 + c) * 64 + kk * 32 + 8 * g];
        acc[0][fn] = __builtin_amdgcn_mfma_f32_16x16x32_bf16(a0, bfr, acc[0][fn], 0, 0, 0);
        acc[1][fn] = __builtin_amdgcn_mfma_f32_16x16x32_bf16(a1, bfr, acc[1][fn], 0, 0, 0);
      }
    }
    __syncthreads();
  }

  #pragma unroll
  for (int fn = 0; fn < 4; ++fn) {
    const int cc = col0 + fn * 16 + c;
    const float bv = HB ? bias[cc] : 0.0f;
    #pragma unroll
    for (int fm = 0; fm < 2; ++fm) {
      #pragma unroll
      for (int r = 0; r < 4; ++r) {
        const int rr = row0 + w * 32 + fm * 16 + 4 * g + r;
        float v = acc[fm][fn][r] + bv;
        if (ACT) v = gelu_exact(v);
        if (RES) v += res[(size_t)rr * Nout + cc];
        if (OBF) ((unsigned short*)Cv)[(size_t)rr * Nout + cc] = f2bf(v);
        else     ((float*)Cv)[(size_t)rr * Nout + cc] = v;
      }
    }
  }
}

// ---------------- bf16 MFMA GEMM (BM=64,BN=64,BK=64): 2x grid for narrow outputs ----------------
// 4 waves in 2x2; wave computes 32x32 (2x2 16x16 frags). LDS 16 KB.
template<int ACT, int RES, int OBF, int HB>
__global__ __launch_bounds__(256, 4) void gemm64_bf16(
    const unsigned short* __restrict__ A, const unsigned short* __restrict__ W,
    const float* __restrict__ bias, const float* __restrict__ res,
    void* __restrict__ Cv, int Nout, int K)
{
  __shared__ unsigned short As[64 * 64];
  __shared__ unsigned short Ws[64 * 64];
  const int tid  = threadIdx.x;
  const int w    = tid >> 6;
  const int lane = tid & 63;
  const int g    = lane >> 4;
  const int c    = lane & 15;
  const int wr   = (w >> 1) * 32;
  const int wc   = (w & 1) * 32;
  const int row0 = blockIdx.x * 64;
  const int col0 = blockIdx.y * 64;
  const f32x4 z = { 0.f, 0.f, 0.f, 0.f };
  f32x4 acc[2][2];
  acc[0][0] = z; acc[0][1] = z; acc[1][0] = z; acc[1][1] = z;

  for (int k0 = 0; k0 < K; k0 += 64) {
    #pragma unroll
    for (int i = 0; i < 2; ++i) {
      const int flat = i * 256 + tid;
      __builtin_amdgcn_global_load_lds(
          (const __attribute__((address_space(1))) void*)(A + (size_t)(row0 + (flat >> 3)) * K + k0 + (flat & 7) * 8),
          (__attribute__((address_space(3))) void*)(&As[flat * 8]), 16, 0, 0);
    }
    #pragma unroll
    for (int i = 0; i < 2; ++i) {
      const int flat = i * 256 + tid;
      __builtin_amdgcn_global_load_lds(
          (const __attribute__((address_space(1))) void*)(W + (size_t)(col0 + (flat >> 3)) * K + k0 + (flat & 7) * 8),
          (__attribute__((address_space(3))) void*)(&Ws[flat * 8]), 16, 0, 0);
    }
    __syncthreads();
    #pragma unroll
    for (int kk = 0; kk < 2; ++kk) {
      const s16x8 a0 = *(const s16x8*)&As[(wr + c) * 64 + kk * 32 + 8 * g];
      const s16x8 a1 = *(const s16x8*)&As[(wr + 16 + c) * 64 + kk * 32 + 8 * g];
      #pragma unroll
      for (int fn = 0; fn < 2; ++fn) {
        const s16x8 bfr = *(const s16x8*)&Ws[(wc + fn * 16 + c) * 64 + kk * 32 + 8 * g];
        acc[0][fn] = __builtin_amdgcn_mfma_f32_16x16x32_bf16(a0, bfr, acc[0][fn], 0, 0, 0);
        acc[1][fn] = __builtin_amdgcn_mfma_f32_16x16x32_bf16(a1, bfr, acc[1][fn], 0, 0, 0);
      }
    }
    __syncthreads();
  }

  #pragma unroll
  for (int fn = 0; fn < 2; ++fn) {
    const int cc = col0 + wc + fn * 16 + c;
    const float bv = HB ? bias[cc] : 0.0f;
    #pragma unroll
    for (int fm = 0; fm < 2; ++fm) {
      #pragma unroll
      for (int r = 0; r < 4; ++r) {
        const int rr = row0 + wr + fm * 16 + 4 * g + r;
        float v = acc[fm][fn][r] + bv;
        if (ACT) v = gelu_exact(v);
        if (RES) v += res[(size_t)rr * Nout + cc];
        if (OBF) ((unsigned short*)Cv)[(size_t)rr * Nout + cc] = f2bf(v);
        else     ((float*)Cv)[(size_t)rr * Nout + cc] = v;
      }
    }
  }
}

// ---------------- V transpose: qkv[:,1024:1536] -> vT[b][h][64][1024] ----------------
__global__ __launch_bounds__(256) void transpose_v(
    const unsigned short* __restrict__ qkv, unsigned short* __restrict__ vT)
{
  const int bid = blockIdx.x;          // b*128 + h*16 + jt
  const int jt = bid & 15, h = (bid >> 4) & 7, b = bid >> 7;
  __shared__ unsigned short t[64][72];
  const int tid = threadIdx.x;
  #pragma unroll
  for (int itr = 0; itr < 2; ++itr) {
    const int flat = itr * 256 + tid;
    const int j = flat >> 3, ch = flat & 7;
    *(u16x8*)&t[j][ch * 8] =
        *(const u16x8*)(qkv + (size_t)(b * 1024 + jt * 64 + j) * 1536 + 1024 + h * 64 + ch * 8);
  }
  __syncthreads();
  #pragma unroll
  for (int itr = 0; itr < 2; ++itr) {
    const int flat = itr * 256 + tid;
    const int dd = flat >> 3, ch = flat & 7;
    u16x8 v;
    #pragma unroll
    for (int e = 0; e < 8; ++e) v[e] = t[ch * 8 + e][dd];
    *(u16x8*)(vT + (size_t)((b * 8 + h) * 64 + dd) * 1024 + jt * 64 + ch * 8) = v;
  }
}

// ---------------- MFMA flash attention, register-prefetched edge bias ----------------
// grid 1024 = b(4) x itile(64) x split(4); 512 thr = 8 waves = 8 heads.
// i-tile 16: each thread owns ONE (i,j) edge pair (16 floats). The next j-tile's
// edge data is prefetched into registers right after the bias barrier, so HBM
// latency hides under QK^T + softmax + PV (T14: register loads survive barriers).
__global__ __launch_bounds__(512, 4) void attn_kernel(
    const unsigned short* __restrict__ qkv, const unsigned short* __restrict__ vT,
    const float* __restrict__ edge, const unsigned char* __restrict__ mask,
    const float* __restrict__ we, const float* __restrict__ web,
    float* __restrict__ pm, float* __restrict__ pl, float* __restrict__ pacc)
{
  __shared__ unsigned short bias_s[8][16][40];  // [h][i][j] bf16, padded
  __shared__ unsigned short p_s[8][16][40];     // per-wave P tile, padded
  __shared__ float we_s[8][16];
  __shared__ float web_s[8];

  const int bid   = blockIdx.x;
  const int split = bid & 3;
  const int it    = (bid >> 2) & 63;
  const int b     = bid >> 8;
  const int i0    = it * 16;
  const int tid   = threadIdx.x;
  const int h     = tid >> 6;
  const int lane  = tid & 63;
  const int g     = lane >> 4;
  const int c     = lane & 15;
  const int pi    = tid >> 5;     // 0..15
  const int pj    = tid & 31;     // 0..31
  const int j0b   = split * 256;

  if (tid < 128) we_s[tid >> 4][tid & 15] = we[tid];
  if (tid < 8)   web_s[tid] = web[tid];

  // Q fragments (held for whole block): 1 fm x 2 kk
  s16x8 qf[2];
  #pragma unroll
  for (int kk = 0; kk < 2; ++kk)
    qf[kk] = *(const s16x8*)(qkv + (size_t)(b * 1024 + i0 + c) * 1536 + h * 64 + kk * 32 + 8 * g);

  const f32x4 z = { 0.f, 0.f, 0.f, 0.f };
  f32x4 o[4];
  #pragma unroll
  for (int fd = 0; fd < 4; ++fd) o[fd] = z;
  float mreg[4], lreg[4];
  #pragma unroll
  for (int r = 0; r < 4; ++r) { mreg[r] = -1e30f; lreg[r] = 0.f; }

  // prologue: prefetch edge tile jc=0 into registers
  float4 er[4];
  {
    const float4* ep = (const float4*)(edge +
        ((((size_t)b << 10) + (i0 + pi)) * 1024 + (j0b + pj)) * 16);
    er[0] = ep[0]; er[1] = ep[1]; er[2] = ep[2]; er[3] = ep[3];
  }

  #pragma unroll
  for (int jc = 0; jc < 8; ++jc) {
    const int j0 = j0b + jc * 32;
    __syncthreads();   // prev bias_s consumers done (iter 0: we_s/web_s ready)

    // --- bias tile from prefetched registers: 16i x 32j, all 8 heads ---
    {
      const float mk = mask[(b << 10) + j0 + pj] ? 0.0f : -1e30f;
      #pragma unroll
      for (int hh = 0; hh < 8; ++hh) {
        const float* wv = we_s[hh];
        const float d =
            er[0].x*wv[0]  + er[0].y*wv[1]  + er[0].z*wv[2]  + er[0].w*wv[3]
          + er[1].x*wv[4]  + er[1].y*wv[5]  + er[1].z*wv[6]  + er[1].w*wv[7]
          + er[2].x*wv[8]  + er[2].y*wv[9]  + er[2].z*wv[10] + er[2].w*wv[11]
          + er[3].x*wv[12] + er[3].y*wv[13] + er[3].z*wv[14] + er[3].w*wv[15];
        bias_s[hh][pi][pj] = f2bf(d + web_s[hh] + mk);
      }
    }
    __syncthreads();   // bias ready

    // --- prefetch next edge tile (overlaps with QK/softmax/PV below) ---
    if (jc < 7) {
      const float4* ep = (const float4*)(edge +
          ((((size_t)b << 10) + (i0 + pi)) * 1024 + (j0 + 32 + pj)) * 16);
      er[0] = ep[0]; er[1] = ep[1]; er[2] = ep[2]; er[3] = ep[3];
    }

    // --- S = Q K^T (per wave / head), 16x32 ---
    f32x4 s[2];
    s[0] = z; s[1] = z;
    #pragma unroll
    for (int fn = 0; fn < 2; ++fn)
      #pragma unroll
      for (int kk = 0; kk < 2; ++kk) {
        const s16x8 kf = *(const s16x8*)(qkv +
            (size_t)(b * 1024 + j0 + fn * 16 + c) * 1536 + 512 + h * 64 + kk * 32 + 8 * g);
        s[fn] = __builtin_amdgcn_mfma_f32_16x16x32_bf16(qf[kk], kf, s[fn], 0, 0, 0);
      }

    // --- scale + bias + online softmax ---
    #pragma unroll
    for (int r = 0; r < 4; ++r) {
      const int irow = 4 * g + r;
      const float s0 = s[0][r] * 0.125f + bf2f(bias_s[h][irow][c]);
      const float s1 = s[1][r] * 0.125f + bf2f(bias_s[h][irow][16 + c]);
      float v = fmaxf(s0, s1);
      v = fmaxf(v, __shfl_xor(v, 1));
      v = fmaxf(v, __shfl_xor(v, 2));
      v = fmaxf(v, __shfl_xor(v, 4));
      v = fmaxf(v, __shfl_xor(v, 8));
      const float nm    = fmaxf(mreg[r], v);
      const float alpha = __expf(mreg[r] - nm);
      mreg[r] = nm;
      const float p0 = __expf(s0 - nm);
      const float p1 = __expf(s1 - nm);
      lreg[r] = lreg[r] * alpha + p0 + p1;
      #pragma unroll
      for (int fd = 0; fd < 4; ++fd) o[fd][r] *= alpha;
      p_s[h][irow][c]      = f2bf(p0);
      p_s[h][irow][16 + c] = f2bf(p1);
    }

    // --- O += P V (per-wave LDS P, V frags from global vT) ---
    const s16x8 pa = *(const s16x8*)&p_s[h][c][8 * g];
    #pragma unroll
    for (int fd = 0; fd < 4; ++fd) {
      const s16x8 vf = *(const s16x8*)(vT +
          (size_t)((b * 8 + h) * 64 + fd * 16 + c) * 1024 + j0 + 8 * g);
      o[fd] = __builtin_amdgcn_mfma_f32_16x16x32_bf16(pa, vf, o[fd], 0, 0, 0);
    }
  }

  // --- epilogue: write partial O, m, l ---
  #pragma unroll
  for (int r = 0; r < 4; ++r) {
    float lv = lreg[r];
    lv += __shfl_xor(lv, 1);
    lv += __shfl_xor(lv, 2);
    lv += __shfl_xor(lv, 4);
    lv += __shfl_xor(lv, 8);
    const int row = ((split * B_SZ + b) * N_HEADS + h) * N_SEQ + i0 + 4 * g + r;
    #pragma unroll
    for (int fd = 0; fd < 4; ++fd)
      pacc[(size_t)row * 64 + fd * 16 + c] = o[fd][r];
    if (c == 0) { pm[row] = mreg[r]; pl[row] = lv; }
  }
}

// ---------------- merge JSPLIT partials -> ao (bf16) ----------------
__global__ __launch_bounds__(256) void merge_kernel(
    const float* __restrict__ pm, const float* __restrict__ pl,
    const float* __restrict__ pacc, unsigned short* __restrict__ ao)
{
  const int row = blockIdx.x * 4 + (threadIdx.x >> 6);   // (b*8+h)*1024 + i
  const int d   = threadIdx.x & 63;
  float ms[JSPLIT], ls[JSPLIT];
  float M = -3e38f;
  #pragma unroll
  for (int s2 = 0; s2 < JSPLIT; ++s2) {
    ms[s2] = pm[s2 * ROWS_T + row];
    ls[s2] = pl[s2 * ROWS_T + row];
    M = fmaxf(M, ms[s2]);
  }
  float acc = 0.f, inv = 0.f;
  if (M > -1e29f) {
    float L = 0.f;
    #pragma unroll
    for (int s2 = 0; s2 < JSPLIT; ++s2) {
      const float wgt = __expf(ms[s2] - M);
      L += ls[s2] * wgt;
      acc += wgt * pacc[((size_t)s2 * ROWS_T + row) * 64 + d];
    }
    inv = 1.0f / L;
  }
  const int b2 = row >> 13, h2 = (row >> 10) & 7, i2 = row & 1023;
  ao[(size_t)(b2 * 1024 + i2) * 512 + h2 * 64 + d] = f2bf(acc * inv);
}

extern "C" void kernel_launch(void* const* d_in, const int* in_sizes, int n_in,
                              void* d_out, int out_size, void* d_ws, size_t ws_size,
                              hipStream_t stream) {
  const float* x    = (const float*)d_in[0];
  const float* edge = (const float*)d_in[1];
  const unsigned char* mask = (const unsigned char*)d_in[2];
  const float* wq   = (const float*)d_in[3];
  const float* wk   = (const float*)d_in[4];
  const float* wv   = (const float*)d_in[5];
  const float* wo   = (const float*)d_in[6];
  const float* wo_b = (const float*)d_in[7];
  const float* we   = (const float*)d_in[8];
  const float* we_b = (const float*)d_in[9];
  const float* g1   = (const float*)d_in[10];
  const float* b1n  = (const float*)d_in[11];
  const float* g2   = (const float*)d_in[12];
  const float* b2n  = (const float*)d_in[13];
  const float* w1   = (const float*)d_in[14];
  const float* b1   = (const float*)d_in[15];
  const float* w2   = (const float*)d_in[16];
  const float* b2   = (const float*)d_in[17];
  float* out = (float*)d_out;
  char* ws = (char*)d_ws;

  const size_t MB = 1048576;
  unsigned short* xn_bf  = (unsigned short*)(ws + 0 * MB);    // 4 MiB  [4096][512]
  unsigned short* qkv_bf = (unsigned short*)(ws + 4 * MB);    // 12 MiB [4096][1536]
  unsigned short* vT     = (unsigned short*)(ws + 16 * MB);   // 4 MiB  [4][8][64][1024]
  unsigned short* ao_bf  = (unsigned short*)(ws + 20 * MB);   // 4 MiB  [4096][512]
  float*          x2     = (float*)(ws + 24 * MB);            // 8 MiB  [4096][512]
  unsigned short* wbf    = (unsigned short*)(ws + 32 * MB);   // 6 MiB  qkv|wo|w1|w2
  float*          pm     = (float*)(ws + 38 * MB);            // 0.5 MiB
  float*          pl     = (float*)(ws + 38 * MB + 524288);   // 0.5 MiB
  float*          pacc   = (float*)(ws + 41 * MB);            // 32 MiB
  unsigned short* hbuf   = (unsigned short*)(ws + 41 * MB);   // 16 MiB (overlays pacc; used after merge)

  unsigned short* wqkv_bf = wbf;
  unsigned short* wo_bf   = wbf + 786432;
  unsigned short* w1_bf   = wbf + 1048576;
  unsigned short* w2_bf   = wbf + 2097152;

  // 1) weight casts
  cast_weights<<<3072, 256, 0, stream>>>(wq, wk, wv, wo, w1, w2, wbf);
  // 2) LN1 -> bf16
  ln_kernel<<<M_ROWS / 4, 256, 0, stream>>>(x, g1, b1n, xn_bf);
  // 3) fused QKV projection: [4096][512] @ [1536][512]^T -> qkv_bf
  {
    dim3 grid(M_ROWS / 128, 1536 / 64);
    gemm_bf16<0, 0, 1, 0><<<grid, 256, 0, stream>>>(xn_bf, wqkv_bf, nullptr, nullptr, qkv_bf, 1536, 512);
  }
  // 4) V transpose
  transpose_v<<<512, 256, 0, stream>>>(qkv_bf, vT);
  // 5) flash attention partials (1024 blocks, register-prefetched edge)
  attn_kernel<<<1024, 512, 0, stream>>>(qkv_bf, vT, edge, mask, we, we_b, pm, pl, pacc);
  // 6) merge -> ao (bf16)
  merge_kernel<<<ROWS_T / 4, 256, 0, stream>>>(pm, pl, pacc, ao_bf);
  // 7) output projection + residual -> x2 (f32)  [64-tile: 512 blocks]
  {
    dim3 grid(M_ROWS / 64, 512 / 64);
    gemm64_bf16<0, 1, 0, 1><<<grid, 256, 0, stream>>>(ao_bf, wo_bf, wo_b, x, (void*)x2, 512, 512);
  }
  // 8) LN2 -> bf16
  ln_kernel<<<M_ROWS / 4, 256, 0, stream>>>(x2, g2, b2n, xn_bf);
  // 9) FFN1 + exact GELU -> hbuf (bf16)
  {
    dim3 grid(M_ROWS / 128, 2048 / 64);
    gemm_bf16<1, 0, 1, 1><<<grid, 256, 0, stream>>>(xn_bf, w1_bf, b1, nullptr, hbuf, 2048, 512);
  }
  // 10) FFN2 + residual -> out (f32)  [64-tile: 512 blocks]
  {
    dim3 grid(M_ROWS / 64, 512 / 64);
    gemm64_bf16<0, 1, 0, 1><<<grid, 256, 0, stream>>>(hbuf, w2_bf, b2, x2, (void*)out, 512, 2048);
  }
}